// Round 5
// baseline (264.251 us; speedup 1.0000x reference)
//
#include <hip/hip_runtime.h>

#define D 256

typedef float f32x4 __attribute__((ext_vector_type(4)));
typedef short short8 __attribute__((ext_vector_type(8)));
typedef __bf16 bf16x8 __attribute__((ext_vector_type(8)));

static __device__ __forceinline__ short f2bs(float f) {
    __bf16 b = (__bf16)f;
    return __builtin_bit_cast(short, b);
}

// async global->LDS, 16B per lane; LDS dest = wave-uniform base + lane*16
static __device__ __forceinline__ void gload_lds16(const short* g, short* l) {
    __builtin_amdgcn_global_load_lds(
        (const __attribute__((address_space(1))) void*)g,
        (__attribute__((address_space(3))) void*)l,
        16, 0, 0);
}

// ---------------- precompute kernels (run every call; deterministic) ----------------

__global__ void pre_bc(const float* __restrict__ b_agg, const float* __restrict__ We1,
                       const float* __restrict__ be1, float* __restrict__ bc)
{
    int j = threadIdx.x;
    float acc = be1[j];
    for (int k = 0; k < D; ++k)
        acc += 2.f * b_agg[k] * We1[k * D + j];
    bc[j] = acc;
}

// Ws[i][k] = W_agg[i*D+k] + W_agg[(i+D)*D+k]; Wc[i][j] = sum_k Ws[i][k]*We1[k][j]
// stored transposed: WcT[j*D+i]
__global__ void pre_wct(const float* __restrict__ W_agg, const float* __restrict__ We1,
                        short* __restrict__ WcT)
{
    __shared__ float wsrow[D];
    int i = blockIdx.x, j = threadIdx.x;
    wsrow[j] = W_agg[i * D + j] + W_agg[(i + D) * D + j];
    __syncthreads();
    float acc = 0.f;
    for (int k = 0; k < D; ++k)
        acc += wsrow[k] * We1[k * D + j];
    WcT[j * D + i] = f2bs(acc);
}

__global__ void pre_wn1t(const float* __restrict__ Wn1, short* __restrict__ Wn1T)
{
    int i = blockIdx.x, j = threadIdx.x;
    Wn1T[j * D + i] = f2bs(Wn1[i * D + j]);
}

__global__ void pre_w2t(const float* __restrict__ We2, const float* __restrict__ Wn2,
                        short* __restrict__ We2T, short* __restrict__ Wn2T)
{
    int k = threadIdx.x;
    for (int c = 0; c < 16; ++c) {
        float ve = (c < 5) ? We2[k * 5 + c] : 0.f;
        float vn = (c < 2) ? Wn2[k * 2 + c] : 0.f;
        We2T[c * D + k] = f2bs(ve);
        Wn2T[c * D + k] = f2bs(vn);
    }
}

// node_feat (fp32) -> bf16 cache in ws
__global__ void pre_featb(const float* __restrict__ f, short* __restrict__ o, int n8)
{
    int i = blockIdx.x * blockDim.x + threadIdx.x;
    if (i >= n8) return;
    const float4* p = reinterpret_cast<const float4*>(f + (size_t)i * 8);
    float4 a = p[0], b = p[1];
    bf16x8 v = {(__bf16)a.x, (__bf16)a.y, (__bf16)a.z, (__bf16)a.w,
                (__bf16)b.x, (__bf16)b.y, (__bf16)b.z, (__bf16)b.w};
    reinterpret_cast<short8*>(o)[i] = __builtin_bit_cast(short8, v);
}

// ---------------- fused v5: global_load_lds staging, MFMA-summed src+dst ----------------
// TILE = 32 rows/block, 4 waves.
// Stage: wave w stages rows [w*8, w*8+8): 4 async 1KB global_load_lds per region
//   (src, and dst for MODE 1). Global address is pre-XOR-swizzled per lane so the
//   linear LDS dest ends up chunk-swizzled (rule #21: swizzle source + read, dest linear).
//   Zero staging VGPRs; all loads in flight; one vmcnt(0) at the barrier.
// GEMM1: wave w owns cols [w*64,w*64+64): 2 M-frags x 4 N-tiles; MODE 1 runs
//   2 MFMAs per frag (src + dst) -> accumulator does the edge sum in fp32.
// h reuses the src region; GEMM2 row-split on waves 0,1.
template<int MODE>
__global__ __launch_bounds__(256, 5)
void fused_mlp_e(const short* __restrict__ featb,
                 const int* __restrict__ pair,
                 const short* __restrict__ W1T,   // [256][256] bf16 bits, transposed
                 const float* __restrict__ bias1, // [256]
                 const short* __restrict__ W2T,   // [16][256] bf16 bits, zero-padded cols
                 const float* __restrict__ bias2, // [ncols]
                 float* __restrict__ out,
                 int nrows, int ncols)
{
    // MODE 1: [0,32) rows src, [32,64) rows dst.  MODE 0: [0,32) rows only.
    __shared__ __align__(16) short sbuf[(MODE ? 64 : 32) * D];

    const int tid = threadIdx.x;
    const int lane = tid & 63;
    const int w = tid >> 6;
    const int l15 = lane & 15;
    const int g = lane >> 4;
    const int rowblk = blockIdx.x * 32;

    // ---- stage: wave w -> rows [w*8, w*8+8), 2 rows per 1KB instruction ----
    {
        const int rl_hi = lane >> 5;   // which of the 2 rows this lane serves
        const int pos = lane & 31;     // 16B chunk within row
        int pv = 0;
        if constexpr (MODE == 1) {
            const int e = 2 * (rowblk + w * 8) + lane;   // 8 edges x {src,dst}
            if (lane < 16 && e < 2 * nrows) pv = pair[e];
        }
#pragma unroll
        for (int j = 0; j < 4; ++j) {
            const int rloc = 2 * j + rl_hi;              // row within wave, 0..7
            const int row = w * 8 + rloc;                // row within block, 0..31
            const int swz = (pos ^ (row & 7)) * 8;       // pre-swizzled element offset
            if constexpr (MODE == 1) {
                const size_t si = (size_t)(unsigned)__shfl(pv, 2 * rloc);
                const size_t di = (size_t)(unsigned)__shfl(pv, 2 * rloc + 1);
                gload_lds16(featb + si * D + swz, &sbuf[(w * 8 + 2 * j) * D]);
                gload_lds16(featb + di * D + swz, &sbuf[(32 + w * 8 + 2 * j) * D]);
            } else {
                int r = rowblk + row;
                if (r > nrows - 1) r = nrows - 1;
                gload_lds16(featb + (size_t)r * D + swz, &sbuf[(w * 8 + 2 * j) * D]);
            }
        }
    }
    asm volatile("s_waitcnt vmcnt(0)" ::: "memory");
    __syncthreads();

    // ---- GEMM1: 32 rows x 256 cols; wave w does cols [w*64, w*64+64) ----
    f32x4 acc[2][4];
#pragma unroll
    for (int f = 0; f < 2; ++f)
#pragma unroll
        for (int t = 0; t < 4; ++t)
            acc[f][t] = f32x4{0.f, 0.f, 0.f, 0.f};

#pragma unroll
    for (int ks = 0; ks < 8; ++ks) {
        const int k0 = ks * 32 + g * 8;
        const int c = ks * 4 + g;
        short8 as[2], ad[2];
#pragma unroll
        for (int f = 0; f < 2; ++f) {
            const int row = f * 16 + l15;
            const int off = row * D + ((c ^ (row & 7)) * 8);
            as[f] = *reinterpret_cast<const short8*>(&sbuf[off]);
            if constexpr (MODE == 1)
                ad[f] = *reinterpret_cast<const short8*>(&sbuf[32 * D + off]);
        }
#pragma unroll
        for (int t = 0; t < 4; ++t) {
            short8 bw = *reinterpret_cast<const short8*>(W1T + ((w * 4 + t) * 16 + l15) * D + k0);
#pragma unroll
            for (int f = 0; f < 2; ++f) {
                acc[f][t] = __builtin_amdgcn_mfma_f32_16x16x32_bf16(as[f], bw, acc[f][t], 0, 0, 0);
                if constexpr (MODE == 1)
                    acc[f][t] = __builtin_amdgcn_mfma_f32_16x16x32_bf16(ad[f], bw, acc[f][t], 0, 0, 0);
            }
        }
    }

    __syncthreads();   // all GEMM1 reads done before h overwrites src region

    // ---- bias + relu -> h into src region (chunk-swizzled) ----
#pragma unroll
    for (int t = 0; t < 4; ++t) {
        const int col = w * 64 + t * 16 + l15;
        const float b = bias1[col];
        const int chunk = col >> 3;
#pragma unroll
        for (int f = 0; f < 2; ++f) {
#pragma unroll
            for (int r = 0; r < 4; ++r) {
                const int row = f * 16 + g * 4 + r;
                float v = fmaxf(acc[f][t][r] + b, 0.f);
                sbuf[row * D + (((chunk ^ (row & 7)) << 3) | (col & 7))] = f2bs(v);
            }
        }
    }

    __syncthreads();

    // ---- GEMM2: h(32x256) @ W2(256x16-padded); waves 0,1 take 16 rows each ----
    if (w < 2) {
        f32x4 a2 = f32x4{0.f, 0.f, 0.f, 0.f};
        const int row = w * 16 + l15;
#pragma unroll
        for (int ks = 0; ks < 8; ++ks) {
            const int k0 = ks * 32 + g * 8;
            const int c = ks * 4 + g;
            short8 bw = *reinterpret_cast<const short8*>(W2T + l15 * D + k0);
            short8 ah = *reinterpret_cast<const short8*>(&sbuf[row * D + ((c ^ (row & 7)) * 8)]);
            a2 = __builtin_amdgcn_mfma_f32_16x16x32_bf16(ah, bw, a2, 0, 0, 0);
        }
        if (l15 < ncols) {
            const float b2 = bias2[l15];
#pragma unroll
            for (int r = 0; r < 4; ++r) {
                const int grow = rowblk + w * 16 + g * 4 + r;
                if (grow < nrows)
                    out[(size_t)grow * ncols + l15] = a2[r] + b2;
            }
        }
    }
}

// ---------------- fallback (fp32 gathers, proven in round 1) ----------------
template<int MODE>
__global__ __launch_bounds__(256, 2)
void fused_mlp(const float* __restrict__ feat,
               const int* __restrict__ pair,
               const short* __restrict__ W1T,
               const float* __restrict__ bias1,
               const short* __restrict__ W2T,
               const float* __restrict__ bias2,
               float* __restrict__ out,
               int nrows, int ncols)
{
    __shared__ short hl[128 * D];

    const int tid = threadIdx.x;
    const int lane = tid & 63;
    const int w = tid >> 6;
    const int l15 = lane & 15;
    const int g = lane >> 4;
    const int rowblk = blockIdx.x * 128 + w * 32;

    const float* ap0[2];
    const float* ap1[2];
#pragma unroll
    for (int f = 0; f < 2; ++f) {
        int r = rowblk + f * 16 + l15;
        if (r > nrows - 1) r = nrows - 1;
        if constexpr (MODE == 0) {
            ap0[f] = feat + (size_t)r * D;
            ap1[f] = nullptr;
        } else {
            ap0[f] = feat + (size_t)pair[2 * r] * D;
            ap1[f] = feat + (size_t)pair[2 * r + 1] * D;
        }
    }

    f32x4 acc[2][16];
#pragma unroll
    for (int f = 0; f < 2; ++f)
#pragma unroll
        for (int t = 0; t < 16; ++t)
            acc[f][t] = f32x4{0.f, 0.f, 0.f, 0.f};

#pragma unroll
    for (int ks = 0; ks < 8; ++ks) {
        const int k0 = ks * 32 + g * 8;
        short8 af[2];
#pragma unroll
        for (int f = 0; f < 2; ++f) {
            const float4* p0 = reinterpret_cast<const float4*>(ap0[f] + k0);
            float4 x0 = p0[0], x1 = p0[1];
            if constexpr (MODE == 1) {
                const float4* p1 = reinterpret_cast<const float4*>(ap1[f] + k0);
                float4 y0 = p1[0], y1 = p1[1];
                x0.x += y0.x; x0.y += y0.y; x0.z += y0.z; x0.w += y0.w;
                x1.x += y1.x; x1.y += y1.y; x1.z += y1.z; x1.w += y1.w;
            }
            bf16x8 bv = {(__bf16)x0.x, (__bf16)x0.y, (__bf16)x0.z, (__bf16)x0.w,
                         (__bf16)x1.x, (__bf16)x1.y, (__bf16)x1.z, (__bf16)x1.w};
            af[f] = __builtin_bit_cast(short8, bv);
        }
#pragma unroll
        for (int t = 0; t < 16; ++t) {
            short8 bw = *reinterpret_cast<const short8*>(W1T + ((t * 16 + l15) * D + k0));
            acc[0][t] = __builtin_amdgcn_mfma_f32_16x16x32_bf16(af[0], bw, acc[0][t], 0, 0, 0);
            acc[1][t] = __builtin_amdgcn_mfma_f32_16x16x32_bf16(af[1], bw, acc[1][t], 0, 0, 0);
        }
    }

#pragma unroll
    for (int t = 0; t < 16; ++t) {
        const int col = t * 16 + l15;
        const float b = bias1[col];
        const int chunk = col >> 3;
#pragma unroll
        for (int f = 0; f < 2; ++f) {
#pragma unroll
            for (int r = 0; r < 4; ++r) {
                const int rl = w * 32 + f * 16 + g * 4 + r;
                float v = fmaxf(acc[f][t][r] + b, 0.f);
                hl[rl * D + ((chunk ^ (rl & 7)) << 3) + (col & 7)] = f2bs(v);
            }
        }
    }

    __syncthreads();

    f32x4 acc2[2];
    acc2[0] = f32x4{0.f, 0.f, 0.f, 0.f};
    acc2[1] = f32x4{0.f, 0.f, 0.f, 0.f};
#pragma unroll
    for (int ks = 0; ks < 8; ++ks) {
        const int k0 = ks * 32 + g * 8;
        const int chunk = k0 >> 3;
        short8 bw = *reinterpret_cast<const short8*>(W2T + (l15 * D + k0));
#pragma unroll
        for (int f = 0; f < 2; ++f) {
            const int rl = w * 32 + f * 16 + l15;
            short8 ah = *reinterpret_cast<const short8*>(&hl[rl * D + ((chunk ^ (rl & 7)) << 3)]);
            acc2[f] = __builtin_amdgcn_mfma_f32_16x16x32_bf16(ah, bw, acc2[f], 0, 0, 0);
        }
    }

    if (l15 < ncols) {
        const float b2 = bias2[l15];
#pragma unroll
        for (int f = 0; f < 2; ++f) {
#pragma unroll
            for (int r = 0; r < 4; ++r) {
                const int grow = rowblk + f * 16 + g * 4 + r;
                if (grow < nrows)
                    out[(size_t)grow * ncols + l15] = acc2[f][r] + b2;
            }
        }
    }
}

// ---------------- launch ----------------

extern "C" void kernel_launch(void* const* d_in, const int* in_sizes, int n_in,
                              void* d_out, int out_size, void* d_ws, size_t ws_size,
                              hipStream_t stream)
{
    const float* node_feat = (const float*)d_in[0];
    const int*   pair_idx  = (const int*)d_in[1];
    const float* W_agg     = (const float*)d_in[2];
    const float* b_agg     = (const float*)d_in[3];
    const float* We1       = (const float*)d_in[4];
    const float* be1       = (const float*)d_in[5];
    const float* We2       = (const float*)d_in[6];
    const float* be2       = (const float*)d_in[7];
    const float* Wn1       = (const float*)d_in[8];
    const float* bn1       = (const float*)d_in[9];
    const float* Wn2       = (const float*)d_in[10];
    const float* bn2       = (const float*)d_in[11];

    const int N = in_sizes[0] / D;   // 100000
    const int E = in_sizes[1] / 2;   // 262144

    float* out = (float*)d_out;
    char*  ws  = (char*)d_ws;

    short* WcT  = (short*)(ws + 0);        // 128 KB
    short* Wn1T = (short*)(ws + 131072);   // 128 KB
    short* We2T = (short*)(ws + 262144);   // 8 KB
    short* Wn2T = (short*)(ws + 270336);   // 8 KB
    float* bc   = (float*)(ws + 278528);   // 1 KB
    const size_t FEATB_OFF = 524288;
    short* featb = (short*)(ws + FEATB_OFF);  // N*D*2 = 51.2 MB
    const size_t need = FEATB_OFF + (size_t)N * D * 2;

    pre_bc<<<1, 256, 0, stream>>>(b_agg, We1, be1, bc);
    pre_wct<<<D, 256, 0, stream>>>(W_agg, We1, WcT);
    pre_wn1t<<<D, 256, 0, stream>>>(Wn1, Wn1T);
    pre_w2t<<<1, 256, 0, stream>>>(We2, Wn2, We2T, Wn2T);

    if (ws_size >= need) {
        const int n8 = N * D / 8;
        pre_featb<<<(n8 + 255) / 256, 256, 0, stream>>>(node_feat, featb, n8);

        fused_mlp_e<0><<<(N + 31) / 32, 256, 0, stream>>>(
            featb, nullptr, Wn1T, bn1, Wn2T, bn2, out, N, 2);

        fused_mlp_e<1><<<(E + 31) / 32, 256, 0, stream>>>(
            featb, pair_idx, WcT, bc, We2T, be2, out + (size_t)2 * N, E, 5);
    } else {
        fused_mlp<0><<<(N + 127) / 128, 256, 0, stream>>>(
            node_feat, nullptr, Wn1T, bn1, Wn2T, bn2, out, N, 2);

        fused_mlp<1><<<E / 128, 256, 0, stream>>>(
            node_feat, pair_idx, WcT, bc, We2T, be2, out + (size_t)2 * N, E, 5);
    }
}

// Round 6
// 174.949 us; speedup vs baseline: 1.5104x; 1.5104x over previous
//
#include <hip/hip_runtime.h>

#define D 256

typedef float f32x4 __attribute__((ext_vector_type(4)));
typedef short short8 __attribute__((ext_vector_type(8)));
typedef __bf16 bf16x8 __attribute__((ext_vector_type(8)));

static __device__ __forceinline__ short f2bs(float f) {
    __bf16 b = (__bf16)f;
    return __builtin_bit_cast(short, b);
}
static __device__ __forceinline__ float bs2f(short s) {
    unsigned u = ((unsigned)(unsigned short)s) << 16;
    return __builtin_bit_cast(float, u);
}

// ---------------- precompute kernels (run every call; deterministic) ----------------

__global__ void pre_bc(const float* __restrict__ b_agg, const float* __restrict__ We1,
                       const float* __restrict__ be1, float* __restrict__ bc)
{
    int j = threadIdx.x;
    float acc = be1[j];
    for (int k = 0; k < D; ++k)
        acc += 2.f * b_agg[k] * We1[k * D + j];
    bc[j] = acc;
}

// Ws[i][k] = W_agg[i*D+k] + W_agg[(i+D)*D+k]; Wc[i][j] = sum_k Ws[i][k]*We1[k][j]
// stored transposed: WcT[j*D+i]
__global__ void pre_wct(const float* __restrict__ W_agg, const float* __restrict__ We1,
                        short* __restrict__ WcT)
{
    __shared__ float wsrow[D];
    int i = blockIdx.x, j = threadIdx.x;
    wsrow[j] = W_agg[i * D + j] + W_agg[(i + D) * D + j];
    __syncthreads();
    float acc = 0.f;
    for (int k = 0; k < D; ++k)
        acc += wsrow[k] * We1[k * D + j];
    WcT[j * D + i] = f2bs(acc);
}

__global__ void pre_wn1t(const float* __restrict__ Wn1, short* __restrict__ Wn1T)
{
    int i = blockIdx.x, j = threadIdx.x;
    Wn1T[j * D + i] = f2bs(Wn1[i * D + j]);
}

__global__ void pre_w2t(const float* __restrict__ We2, const float* __restrict__ Wn2,
                        short* __restrict__ We2T, short* __restrict__ Wn2T)
{
    int k = threadIdx.x;
    for (int c = 0; c < 16; ++c) {
        float ve = (c < 5) ? We2[k * 5 + c] : 0.f;
        float vn = (c < 2) ? Wn2[k * 2 + c] : 0.f;
        We2T[c * D + k] = f2bs(ve);
        Wn2T[c * D + k] = f2bs(vn);
    }
}

// ---------------- dense fused GEMM: H' = nf@Wc + bc/2 ; node_res = relu(nf@Wn1+bn1)@Wn2+bn2 ----
// 512 threads = 8 waves; 64 rows/block; N=512 (cols 0-255: Wc half -> H, 256-511: Wn1 half).
// Wave w owns cols [w*64, w*64+64): 4 M-frags x 4 N-tiles, acc = 64 VGPR.
// A-tile (64x256 bf16, chunk-XOR-swizzled) staged from fp32 once; weights stream from L2.
__global__ __launch_bounds__(512, 4)
void node_h_gemm(const float* __restrict__ nf,
                 const short* __restrict__ WcT, const short* __restrict__ Wn1T,
                 const float* __restrict__ bc,  const float* __restrict__ bn1,
                 const short* __restrict__ Wn2T, const float* __restrict__ bn2,
                 short* __restrict__ H, float* __restrict__ outn, int nrows)
{
    __shared__ __align__(16) short sA[64 * D];   // A tile; reused as plain Ht for coalesced store
    __shared__ __align__(16) short hl[64 * D];   // node-half relu'd h (swizzled)

    const int tid = threadIdx.x;
    const int lane = tid & 63;
    const int w = tid >> 6;        // 0..7
    const int l15 = lane & 15;
    const int g = lane >> 4;
    const int rowblk = blockIdx.x * 64;

    // ---- stage A: fp32 -> bf16, chunk-swizzled.  thread t: row t>>3, 32-float seg t&7 ----
    {
        const int row = tid >> 3;
        const int q = tid & 7;
        int r = rowblk + row; if (r > nrows - 1) r = nrows - 1;
        const float4* p = reinterpret_cast<const float4*>(nf + (size_t)r * D + q * 32);
#pragma unroll
        for (int j = 0; j < 4; ++j) {
            float4 x0 = p[2 * j], x1 = p[2 * j + 1];
            bf16x8 v = {(__bf16)x0.x, (__bf16)x0.y, (__bf16)x0.z, (__bf16)x0.w,
                        (__bf16)x1.x, (__bf16)x1.y, (__bf16)x1.z, (__bf16)x1.w};
            const int c = q * 4 + j;
            *reinterpret_cast<short8*>(&sA[row * D + ((c ^ (row & 7)) * 8)]) =
                __builtin_bit_cast(short8, v);
        }
    }
    __syncthreads();

    const short* Wb = (w < 4) ? WcT : Wn1T;
    const int nc0 = (w & 3) * 4;

    f32x4 acc[4][4];
#pragma unroll
    for (int f = 0; f < 4; ++f)
#pragma unroll
        for (int t = 0; t < 4; ++t)
            acc[f][t] = f32x4{0.f, 0.f, 0.f, 0.f};

#pragma unroll
    for (int ks = 0; ks < 8; ++ks) {
        const int k0 = ks * 32 + g * 8;
        const int c = ks * 4 + g;
        short8 a[4];
#pragma unroll
        for (int f = 0; f < 4; ++f) {
            const int row = f * 16 + l15;
            a[f] = *reinterpret_cast<const short8*>(&sA[row * D + ((c ^ (row & 7)) * 8)]);
        }
#pragma unroll
        for (int t = 0; t < 4; ++t) {
            short8 bw = *reinterpret_cast<const short8*>(Wb + ((nc0 + t) * 16 + l15) * D + k0);
#pragma unroll
            for (int f = 0; f < 4; ++f)
                acc[f][t] = __builtin_amdgcn_mfma_f32_16x16x32_bf16(a[f], bw, acc[f][t], 0, 0, 0);
        }
    }

    __syncthreads();   // all sA reads done before reuse

    if (w < 4) {
        // H half: Ht = bf16(acc + 0.5*bc[col]) into sA, plain [64][256] layout
#pragma unroll
        for (int t = 0; t < 4; ++t) {
            const int col = w * 64 + t * 16 + l15;
            const float bb = 0.5f * bc[col];
#pragma unroll
            for (int f = 0; f < 4; ++f)
#pragma unroll
                for (int r = 0; r < 4; ++r) {
                    const int row = f * 16 + g * 4 + r;
                    sA[row * D + col] = f2bs(acc[f][t][r] + bb);
                }
        }
    } else {
        // node half: hl = relu(acc + bn1), chunk-swizzled for GEMM2 ds_read_b128
#pragma unroll
        for (int t = 0; t < 4; ++t) {
            const int col = (w - 4) * 64 + t * 16 + l15;
            const float bb = bn1[col];
            const int chunk = col >> 3;
#pragma unroll
            for (int f = 0; f < 4; ++f)
#pragma unroll
                for (int r = 0; r < 4; ++r) {
                    const int row = f * 16 + g * 4 + r;
                    float v = fmaxf(acc[f][t][r] + bb, 0.f);
                    hl[row * D + (((chunk ^ (row & 7)) << 3) | (col & 7))] = f2bs(v);
                }
        }
    }

    __syncthreads();

    if (w < 4) {
        // coalesced H store: wave w rows [w*16, w*16+16); 4 lanes/row x 8 chunks
        const int row = w * 16 + (lane >> 2);
        const int grow = rowblk + row;
#pragma unroll
        for (int j = 0; j < 8; ++j) {
            const int ch = (lane & 3) * 8 + j;
            short8 v = *reinterpret_cast<const short8*>(&sA[row * D + ch * 8]);
            if (grow < nrows)
                *reinterpret_cast<short8*>(H + (size_t)grow * D + ch * 8) = v;
        }
    } else {
        // node GEMM2: h(16x256) @ Wn2(256x16-padded) per wave
        const int vr = w - 4;
        const int row = vr * 16 + l15;
        f32x4 a2 = f32x4{0.f, 0.f, 0.f, 0.f};
#pragma unroll
        for (int ks = 0; ks < 8; ++ks) {
            const int k0 = ks * 32 + g * 8;
            const int c = ks * 4 + g;
            short8 bw = *reinterpret_cast<const short8*>(Wn2T + l15 * D + k0);
            short8 ah = *reinterpret_cast<const short8*>(&hl[row * D + ((c ^ (row & 7)) * 8)]);
            a2 = __builtin_amdgcn_mfma_f32_16x16x32_bf16(ah, bw, a2, 0, 0, 0);
        }
        if (l15 < 2) {
            const float b2 = bn2[l15];
#pragma unroll
            for (int r = 0; r < 4; ++r) {
                const int grow = rowblk + vr * 16 + g * 4 + r;
                if (grow < nrows)
                    outn[(size_t)grow * 2 + l15] = a2[r] + b2;
            }
        }
    }
}

// ---------------- edge kernel: out = relu(H[src]+H[dst])@We2 + be2 ----------------
// No LDS.  4 waves x 4 groups x 16 edges = 256 edges/block.  Per group: 16 gather
// loads (16B/lane) issued up front, fp32 add+relu+cvt in regs, 8 MFMAs vs
// register-resident We2T fragments.  Pure gather-BW bound (H is L3-resident).
__global__ __launch_bounds__(256, 4)
void edge_gemv(const short* __restrict__ H, const int* __restrict__ pair,
               const short* __restrict__ We2T, const float* __restrict__ be2,
               float* __restrict__ out, int nedges)
{
    const int lane = threadIdx.x & 63;
    const int w = threadIdx.x >> 6;
    const int l15 = lane & 15;
    const int g = lane >> 4;

    short8 Bf[8];
#pragma unroll
    for (int ks = 0; ks < 8; ++ks)
        Bf[ks] = *reinterpret_cast<const short8*>(We2T + l15 * D + ks * 32 + g * 8);

    const float b2 = (l15 < 5) ? be2[l15] : 0.f;
    const int base = blockIdx.x * 256 + w * 64;

#pragma unroll
    for (int grp = 0; grp < 4; ++grp) {
        int e = base + grp * 16 + l15;
        if (e > nedges - 1) e = nedges - 1;
        const size_t si = (size_t)(unsigned)pair[2 * e];
        const size_t di = (size_t)(unsigned)pair[2 * e + 1];
        const short8* sp = reinterpret_cast<const short8*>(H + si * D + g * 8);
        const short8* dp = reinterpret_cast<const short8*>(H + di * D + g * 8);
        short8 sv[8], dv[8];
#pragma unroll
        for (int ks = 0; ks < 8; ++ks) {
            sv[ks] = sp[ks * 4];
            dv[ks] = dp[ks * 4];
        }
        f32x4 acc = f32x4{0.f, 0.f, 0.f, 0.f};
#pragma unroll
        for (int ks = 0; ks < 8; ++ks) {
            short8 a;
#pragma unroll
            for (int i = 0; i < 8; ++i)
                a[i] = f2bs(fmaxf(bs2f(sv[ks][i]) + bs2f(dv[ks][i]), 0.f));
            acc = __builtin_amdgcn_mfma_f32_16x16x32_bf16(a, Bf[ks], acc, 0, 0, 0);
        }
        if (l15 < 5) {
#pragma unroll
            for (int r = 0; r < 4; ++r) {
                const int ge = base + grp * 16 + g * 4 + r;
                if (ge < nedges)
                    out[(size_t)ge * 5 + l15] = acc[r] + b2;
            }
        }
    }
}

// ---------------- fallback (fp32 gathers, proven in round 1) ----------------
template<int MODE>
__global__ __launch_bounds__(256, 2)
void fused_mlp(const float* __restrict__ feat,
               const int* __restrict__ pair,
               const short* __restrict__ W1T,
               const float* __restrict__ bias1,
               const short* __restrict__ W2T,
               const float* __restrict__ bias2,
               float* __restrict__ out,
               int nrows, int ncols)
{
    __shared__ short hl[128 * D];

    const int tid = threadIdx.x;
    const int lane = tid & 63;
    const int w = tid >> 6;
    const int l15 = lane & 15;
    const int g = lane >> 4;
    const int rowblk = blockIdx.x * 128 + w * 32;

    const float* ap0[2];
    const float* ap1[2];
#pragma unroll
    for (int f = 0; f < 2; ++f) {
        int r = rowblk + f * 16 + l15;
        if (r > nrows - 1) r = nrows - 1;
        if constexpr (MODE == 0) {
            ap0[f] = feat + (size_t)r * D;
            ap1[f] = nullptr;
        } else {
            ap0[f] = feat + (size_t)pair[2 * r] * D;
            ap1[f] = feat + (size_t)pair[2 * r + 1] * D;
        }
    }

    f32x4 acc[2][16];
#pragma unroll
    for (int f = 0; f < 2; ++f)
#pragma unroll
        for (int t = 0; t < 16; ++t)
            acc[f][t] = f32x4{0.f, 0.f, 0.f, 0.f};

#pragma unroll
    for (int ks = 0; ks < 8; ++ks) {
        const int k0 = ks * 32 + g * 8;
        short8 af[2];
#pragma unroll
        for (int f = 0; f < 2; ++f) {
            const float4* p0 = reinterpret_cast<const float4*>(ap0[f] + k0);
            float4 x0 = p0[0], x1 = p0[1];
            if constexpr (MODE == 1) {
                const float4* p1 = reinterpret_cast<const float4*>(ap1[f] + k0);
                float4 y0 = p1[0], y1 = p1[1];
                x0.x += y0.x; x0.y += y0.y; x0.z += y0.z; x0.w += y0.w;
                x1.x += y1.x; x1.y += y1.y; x1.z += y1.z; x1.w += y1.w;
            }
            bf16x8 bv = {(__bf16)x0.x, (__bf16)x0.y, (__bf16)x0.z, (__bf16)x0.w,
                         (__bf16)x1.x, (__bf16)x1.y, (__bf16)x1.z, (__bf16)x1.w};
            af[f] = __builtin_bit_cast(short8, bv);
        }
#pragma unroll
        for (int t = 0; t < 16; ++t) {
            short8 bw = *reinterpret_cast<const short8*>(W1T + ((t * 16 + l15) * D + k0));
            acc[0][t] = __builtin_amdgcn_mfma_f32_16x16x32_bf16(af[0], bw, acc[0][t], 0, 0, 0);
            acc[1][t] = __builtin_amdgcn_mfma_f32_16x16x32_bf16(af[1], bw, acc[1][t], 0, 0, 0);
        }
    }

#pragma unroll
    for (int t = 0; t < 16; ++t) {
        const int col = t * 16 + l15;
        const float b = bias1[col];
        const int chunk = col >> 3;
#pragma unroll
        for (int f = 0; f < 2; ++f) {
#pragma unroll
            for (int r = 0; r < 4; ++r) {
                const int rl = w * 32 + f * 16 + g * 4 + r;
                float v = fmaxf(acc[f][t][r] + b, 0.f);
                hl[rl * D + ((chunk ^ (rl & 7)) << 3) + (col & 7)] = f2bs(v);
            }
        }
    }

    __syncthreads();

    f32x4 acc2[2];
    acc2[0] = f32x4{0.f, 0.f, 0.f, 0.f};
    acc2[1] = f32x4{0.f, 0.f, 0.f, 0.f};
#pragma unroll
    for (int ks = 0; ks < 8; ++ks) {
        const int k0 = ks * 32 + g * 8;
        const int chunk = k0 >> 3;
        short8 bw = *reinterpret_cast<const short8*>(W2T + (l15 * D + k0));
#pragma unroll
        for (int f = 0; f < 2; ++f) {
            const int rl = w * 32 + f * 16 + l15;
            short8 ah = *reinterpret_cast<const short8*>(&hl[rl * D + ((chunk ^ (rl & 7)) << 3)]);
            acc2[f] = __builtin_amdgcn_mfma_f32_16x16x32_bf16(ah, bw, acc2[f], 0, 0, 0);
        }
    }

    if (l15 < ncols) {
        const float b2 = bias2[l15];
#pragma unroll
        for (int f = 0; f < 2; ++f) {
#pragma unroll
            for (int r = 0; r < 4; ++r) {
                const int grow = rowblk + f * 16 + g * 4 + r;
                if (grow < nrows)
                    out[(size_t)grow * ncols + l15] = acc2[f][r] + b2;
            }
        }
    }
}

// ---------------- launch ----------------

extern "C" void kernel_launch(void* const* d_in, const int* in_sizes, int n_in,
                              void* d_out, int out_size, void* d_ws, size_t ws_size,
                              hipStream_t stream)
{
    const float* node_feat = (const float*)d_in[0];
    const int*   pair_idx  = (const int*)d_in[1];
    const float* W_agg     = (const float*)d_in[2];
    const float* b_agg     = (const float*)d_in[3];
    const float* We1       = (const float*)d_in[4];
    const float* be1       = (const float*)d_in[5];
    const float* We2       = (const float*)d_in[6];
    const float* be2       = (const float*)d_in[7];
    const float* Wn1       = (const float*)d_in[8];
    const float* bn1       = (const float*)d_in[9];
    const float* Wn2       = (const float*)d_in[10];
    const float* bn2       = (const float*)d_in[11];

    const int N = in_sizes[0] / D;   // 100000
    const int E = in_sizes[1] / 2;   // 262144

    float* out = (float*)d_out;
    char*  ws  = (char*)d_ws;

    short* WcT  = (short*)(ws + 0);        // 128 KB
    short* Wn1T = (short*)(ws + 131072);   // 128 KB
    short* We2T = (short*)(ws + 262144);   // 8 KB
    short* Wn2T = (short*)(ws + 270336);   // 8 KB
    float* bc   = (float*)(ws + 278528);   // 1 KB
    const size_t H_OFF = 524288;
    short* H = (short*)(ws + H_OFF);       // N*D*2 = 51.2 MB
    const size_t need = H_OFF + (size_t)N * D * 2;

    pre_bc<<<1, 256, 0, stream>>>(b_agg, We1, be1, bc);
    pre_wct<<<D, 256, 0, stream>>>(W_agg, We1, WcT);
    pre_wn1t<<<D, 256, 0, stream>>>(Wn1, Wn1T);
    pre_w2t<<<1, 256, 0, stream>>>(We2, Wn2, We2T, Wn2T);

    if (ws_size >= need) {
        node_h_gemm<<<(N + 63) / 64, 512, 0, stream>>>(
            node_feat, WcT, Wn1T, bc, bn1, Wn2T, bn2, H, out, N);

        edge_gemv<<<(E + 255) / 256, 256, 0, stream>>>(
            H, pair_idx, We2T, be2, out + (size_t)2 * N, E);
    } else {
        fused_mlp<0><<<(N + 127) / 128, 256, 0, stream>>>(
            node_feat, nullptr, Wn1T, bn1, Wn2T, bn2, out, N, 2);

        fused_mlp<1><<<E / 128, 256, 0, stream>>>(
            node_feat, pair_idx, WcT, bc, We2T, be2, out + (size_t)2 * N, E, 5);
    }
}

// Round 7
// 168.437 us; speedup vs baseline: 1.5688x; 1.0387x over previous
//
#include <hip/hip_runtime.h>

#define D 256

typedef float f32x4 __attribute__((ext_vector_type(4)));
typedef short short8 __attribute__((ext_vector_type(8)));
typedef __bf16 bf16x8 __attribute__((ext_vector_type(8)));

static __device__ __forceinline__ short f2bs(float f) {
    __bf16 b = (__bf16)f;
    return __builtin_bit_cast(short, b);
}
static __device__ __forceinline__ float bs2f(short s) {
    unsigned u = ((unsigned)(unsigned short)s) << 16;
    return __builtin_bit_cast(float, u);
}

// ---------------- precompute kernels (run every call; deterministic) ----------------

__global__ void pre_bc(const float* __restrict__ b_agg, const float* __restrict__ We1,
                       const float* __restrict__ be1, float* __restrict__ bc)
{
    int j = threadIdx.x;
    float acc = be1[j];
    for (int k = 0; k < D; ++k)
        acc += 2.f * b_agg[k] * We1[k * D + j];
    bc[j] = acc;
}

// Ws[i][k] = W_agg[i*D+k] + W_agg[(i+D)*D+k]; Wc[i][j] = sum_k Ws[i][k]*We1[k][j]
// stored transposed: WcT[j*D+i]
__global__ void pre_wct(const float* __restrict__ W_agg, const float* __restrict__ We1,
                        short* __restrict__ WcT)
{
    __shared__ float wsrow[D];
    int i = blockIdx.x, j = threadIdx.x;
    wsrow[j] = W_agg[i * D + j] + W_agg[(i + D) * D + j];
    __syncthreads();
    float acc = 0.f;
    for (int k = 0; k < D; ++k)
        acc += wsrow[k] * We1[k * D + j];
    WcT[j * D + i] = f2bs(acc);
}

__global__ void pre_wn1t(const float* __restrict__ Wn1, short* __restrict__ Wn1T)
{
    int i = blockIdx.x, j = threadIdx.x;
    Wn1T[j * D + i] = f2bs(Wn1[i * D + j]);
}

__global__ void pre_w2t(const float* __restrict__ We2, const float* __restrict__ Wn2,
                        short* __restrict__ We2T, short* __restrict__ Wn2T)
{
    int k = threadIdx.x;
    for (int c = 0; c < 16; ++c) {
        float ve = (c < 5) ? We2[k * 5 + c] : 0.f;
        float vn = (c < 2) ? Wn2[k * 2 + c] : 0.f;
        We2T[c * D + k] = f2bs(ve);
        Wn2T[c * D + k] = f2bs(vn);
    }
}

// ---------------- node GEMM v2: weights in registers, pure-LDS k-loop ----------------
// H' = nf@Wc + bc/2 (bf16 -> ws);  node_res = relu(nf@Wn1+bn1)@Wn2 + bn2 -> out.
// 512 threads = 8 waves; 64 rows/block; 512 cols (waves 0-3: Wc -> H, 4-7: Wn1 -> node).
// Per wave: B = 4 N-tiles x 8 ksteps x short8 = 128 VGPR, loaded ONCE before the k-loop.
// A tile in LDS, FRAGMENT-ORDER layout: frag i = ks*256 + f*64 + lane (16B each) so both
// staging ds_write_b128 and GEMM ds_read_b128 are lane-stride-1 (conflict-free).
// H is stored directly from accumulators to global (no LDS round-trip).
__global__ __launch_bounds__(512, 2)
void node_h_gemm2(const float* __restrict__ nf,
                  const short* __restrict__ WcT, const short* __restrict__ Wn1T,
                  const float* __restrict__ bc,  const float* __restrict__ bn1,
                  const short* __restrict__ Wn2T, const float* __restrict__ bn2,
                  short* __restrict__ H, float* __restrict__ outn, int nrows)
{
    __shared__ __align__(16) short sA[2048 * 8];  // 32 KB, fragment-order A tile
    __shared__ __align__(16) short hl[64 * D];    // 32 KB, node-half relu'd h (swizzled)

    const int tid = threadIdx.x;
    const int lane = tid & 63;
    const int w = tid >> 6;        // 0..7
    const int l15 = lane & 15;
    const int g = lane >> 4;
    const int rowblk = blockIdx.x * 64;

    // ---- hoist this wave's weight fragments into registers (once) ----
    const short* Wb = (w < 4) ? WcT : Wn1T;
    const int nc0 = (w & 3) * 4;
    short8 Bw[4][8];
#pragma unroll
    for (int t = 0; t < 4; ++t)
#pragma unroll
        for (int ks = 0; ks < 8; ++ks)
            Bw[t][ks] = *reinterpret_cast<const short8*>(
                Wb + ((nc0 + t) * 16 + l15) * D + ks * 32 + g * 8);

    // ---- stage A: fp32 -> bf16 into fragment-order LDS ----
    // frag i = ks*256 + f*64 + g*16 + l15 holds nf[row=rowblk+f*16+l15][ks*32+g*8 .. +8]
#pragma unroll
    for (int j = 0; j < 4; ++j) {
        const int i = j * 512 + tid;
        const int li = i & 15, gi = (i >> 4) & 3, fi = (i >> 6) & 3, ki = i >> 8;
        int r = rowblk + fi * 16 + li;
        if (r > nrows - 1) r = nrows - 1;
        const float4* p = reinterpret_cast<const float4*>(nf + (size_t)r * D + ki * 32 + gi * 8);
        float4 x0 = p[0], x1 = p[1];
        bf16x8 v = {(__bf16)x0.x, (__bf16)x0.y, (__bf16)x0.z, (__bf16)x0.w,
                    (__bf16)x1.x, (__bf16)x1.y, (__bf16)x1.z, (__bf16)x1.w};
        *reinterpret_cast<short8*>(&sA[i * 8]) = __builtin_bit_cast(short8, v);
    }
    __syncthreads();

    // ---- k-loop: pure LDS + MFMA ----
    f32x4 acc[4][4];
#pragma unroll
    for (int f = 0; f < 4; ++f)
#pragma unroll
        for (int t = 0; t < 4; ++t)
            acc[f][t] = f32x4{0.f, 0.f, 0.f, 0.f};

#pragma unroll
    for (int ks = 0; ks < 8; ++ks) {
        short8 a[4];
#pragma unroll
        for (int f = 0; f < 4; ++f)
            a[f] = *reinterpret_cast<const short8*>(&sA[(ks * 256 + f * 64 + lane) * 8]);
#pragma unroll
        for (int t = 0; t < 4; ++t)
#pragma unroll
            for (int f = 0; f < 4; ++f)
                acc[f][t] = __builtin_amdgcn_mfma_f32_16x16x32_bf16(a[f], Bw[t][ks], acc[f][t], 0, 0, 0);
    }

    if (w < 4) {
        // ---- H half: H[row][col] = bf16(acc + 0.5*bc[col]), direct global scatter ----
#pragma unroll
        for (int t = 0; t < 4; ++t) {
            const int col = w * 64 + t * 16 + l15;
            const float bb = 0.5f * bc[col];
#pragma unroll
            for (int f = 0; f < 4; ++f)
#pragma unroll
                for (int r = 0; r < 4; ++r) {
                    const int grow = rowblk + f * 16 + g * 4 + r;
                    if (grow < nrows)
                        H[(size_t)grow * D + col] = f2bs(acc[f][t][r] + bb);
                }
        }
    } else {
        // ---- node half: hl = relu(acc + bn1), chunk-swizzled for GEMM2 ----
#pragma unroll
        for (int t = 0; t < 4; ++t) {
            const int col = (w - 4) * 64 + t * 16 + l15;
            const float bb = bn1[col];
            const int chunk = col >> 3;
#pragma unroll
            for (int f = 0; f < 4; ++f)
#pragma unroll
                for (int r = 0; r < 4; ++r) {
                    const int row = f * 16 + g * 4 + r;
                    float v = fmaxf(acc[f][t][r] + bb, 0.f);
                    hl[row * D + (((chunk ^ (row & 7)) << 3) | (col & 7))] = f2bs(v);
                }
        }
    }

    __syncthreads();

    if (w >= 4) {
        // ---- node GEMM2: h(16x256) @ Wn2(256x16-padded) per wave ----
        const int vr = w - 4;
        const int row = vr * 16 + l15;
        f32x4 a2 = f32x4{0.f, 0.f, 0.f, 0.f};
#pragma unroll
        for (int ks = 0; ks < 8; ++ks) {
            const int k0 = ks * 32 + g * 8;
            const int c = ks * 4 + g;
            short8 bw = *reinterpret_cast<const short8*>(Wn2T + l15 * D + k0);
            short8 ah = *reinterpret_cast<const short8*>(&hl[row * D + ((c ^ (row & 7)) * 8)]);
            a2 = __builtin_amdgcn_mfma_f32_16x16x32_bf16(ah, bw, a2, 0, 0, 0);
        }
        if (l15 < 2) {
            const float b2 = bn2[l15];
#pragma unroll
            for (int r = 0; r < 4; ++r) {
                const int grow = rowblk + vr * 16 + g * 4 + r;
                if (grow < nrows)
                    outn[(size_t)grow * 2 + l15] = a2[r] + b2;
            }
        }
    }
}

// ---------------- edge kernel: out = relu(H[src]+H[dst])@We2 + be2 ----------------
// No LDS.  4 waves x 4 groups x 16 edges = 256 edges/block.  Per group: 16 gather
// loads (16B/lane) issued up front, fp32 add+relu+cvt in regs, 8 MFMAs vs
// register-resident We2T fragments.  Pure gather-BW bound (H is L3-resident).
__global__ __launch_bounds__(256, 4)
void edge_gemv(const short* __restrict__ H, const int* __restrict__ pair,
               const short* __restrict__ We2T, const float* __restrict__ be2,
               float* __restrict__ out, int nedges)
{
    const int lane = threadIdx.x & 63;
    const int w = threadIdx.x >> 6;
    const int l15 = lane & 15;
    const int g = lane >> 4;

    short8 Bf[8];
#pragma unroll
    for (int ks = 0; ks < 8; ++ks)
        Bf[ks] = *reinterpret_cast<const short8*>(We2T + l15 * D + ks * 32 + g * 8);

    const float b2 = (l15 < 5) ? be2[l15] : 0.f;
    const int base = blockIdx.x * 256 + w * 64;

#pragma unroll
    for (int grp = 0; grp < 4; ++grp) {
        int e = base + grp * 16 + l15;
        if (e > nedges - 1) e = nedges - 1;
        const size_t si = (size_t)(unsigned)pair[2 * e];
        const size_t di = (size_t)(unsigned)pair[2 * e + 1];
        const short8* sp = reinterpret_cast<const short8*>(H + si * D + g * 8);
        const short8* dp = reinterpret_cast<const short8*>(H + di * D + g * 8);
        short8 sv[8], dv[8];
#pragma unroll
        for (int ks = 0; ks < 8; ++ks) {
            sv[ks] = sp[ks * 4];
            dv[ks] = dp[ks * 4];
        }
        f32x4 acc = f32x4{0.f, 0.f, 0.f, 0.f};
#pragma unroll
        for (int ks = 0; ks < 8; ++ks) {
            short8 a;
#pragma unroll
            for (int i = 0; i < 8; ++i)
                a[i] = f2bs(fmaxf(bs2f(sv[ks][i]) + bs2f(dv[ks][i]), 0.f));
            acc = __builtin_amdgcn_mfma_f32_16x16x32_bf16(a, Bf[ks], acc, 0, 0, 0);
        }
        if (l15 < 5) {
#pragma unroll
            for (int r = 0; r < 4; ++r) {
                const int ge = base + grp * 16 + g * 4 + r;
                if (ge < nedges)
                    out[(size_t)ge * 5 + l15] = acc[r] + b2;
            }
        }
    }
}

// ---------------- fallback (fp32 gathers, proven in round 1) ----------------
template<int MODE>
__global__ __launch_bounds__(256, 2)
void fused_mlp(const float* __restrict__ feat,
               const int* __restrict__ pair,
               const short* __restrict__ W1T,
               const float* __restrict__ bias1,
               const short* __restrict__ W2T,
               const float* __restrict__ bias2,
               float* __restrict__ out,
               int nrows, int ncols)
{
    __shared__ short hl[128 * D];

    const int tid = threadIdx.x;
    const int lane = tid & 63;
    const int w = tid >> 6;
    const int l15 = lane & 15;
    const int g = lane >> 4;
    const int rowblk = blockIdx.x * 128 + w * 32;

    const float* ap0[2];
    const float* ap1[2];
#pragma unroll
    for (int f = 0; f < 2; ++f) {
        int r = rowblk + f * 16 + l15;
        if (r > nrows - 1) r = nrows - 1;
        if constexpr (MODE == 0) {
            ap0[f] = feat + (size_t)r * D;
            ap1[f] = nullptr;
        } else {
            ap0[f] = feat + (size_t)pair[2 * r] * D;
            ap1[f] = feat + (size_t)pair[2 * r + 1] * D;
        }
    }

    f32x4 acc[2][16];
#pragma unroll
    for (int f = 0; f < 2; ++f)
#pragma unroll
        for (int t = 0; t < 16; ++t)
            acc[f][t] = f32x4{0.f, 0.f, 0.f, 0.f};

#pragma unroll
    for (int ks = 0; ks < 8; ++ks) {
        const int k0 = ks * 32 + g * 8;
        short8 af[2];
#pragma unroll
        for (int f = 0; f < 2; ++f) {
            const float4* p0 = reinterpret_cast<const float4*>(ap0[f] + k0);
            float4 x0 = p0[0], x1 = p0[1];
            if constexpr (MODE == 1) {
                const float4* p1 = reinterpret_cast<const float4*>(ap1[f] + k0);
                float4 y0 = p1[0], y1 = p1[1];
                x0.x += y0.x; x0.y += y0.y; x0.z += y0.z; x0.w += y0.w;
                x1.x += y1.x; x1.y += y1.y; x1.z += y1.z; x1.w += y1.w;
            }
            bf16x8 bv = {(__bf16)x0.x, (__bf16)x0.y, (__bf16)x0.z, (__bf16)x0.w,
                         (__bf16)x1.x, (__bf16)x1.y, (__bf16)x1.z, (__bf16)x1.w};
            af[f] = __builtin_bit_cast(short8, bv);
        }
#pragma unroll
        for (int t = 0; t < 16; ++t) {
            short8 bw = *reinterpret_cast<const short8*>(W1T + ((t * 16 + l15) * D + k0));
            acc[0][t] = __builtin_amdgcn_mfma_f32_16x16x32_bf16(af[0], bw, acc[0][t], 0, 0, 0);
            acc[1][t] = __builtin_amdgcn_mfma_f32_16x16x32_bf16(af[1], bw, acc[1][t], 0, 0, 0);
        }
    }

#pragma unroll
    for (int t = 0; t < 16; ++t) {
        const int col = t * 16 + l15;
        const float b = bias1[col];
        const int chunk = col >> 3;
#pragma unroll
        for (int f = 0; f < 2; ++f) {
#pragma unroll
            for (int r = 0; r < 4; ++r) {
                const int rl = w * 32 + f * 16 + g * 4 + r;
                float v = fmaxf(acc[f][t][r] + b, 0.f);
                hl[rl * D + ((chunk ^ (rl & 7)) << 3) + (col & 7)] = f2bs(v);
            }
        }
    }

    __syncthreads();

    f32x4 acc2[2];
    acc2[0] = f32x4{0.f, 0.f, 0.f, 0.f};
    acc2[1] = f32x4{0.f, 0.f, 0.f, 0.f};
#pragma unroll
    for (int ks = 0; ks < 8; ++ks) {
        const int k0 = ks * 32 + g * 8;
        const int chunk = k0 >> 3;
        short8 bw = *reinterpret_cast<const short8*>(W2T + (l15 * D + k0));
#pragma unroll
        for (int f = 0; f < 2; ++f) {
            const int rl = w * 32 + f * 16 + l15;
            short8 ah = *reinterpret_cast<const short8*>(&hl[rl * D + ((chunk ^ (rl & 7)) << 3)]);
            acc2[f] = __builtin_amdgcn_mfma_f32_16x16x32_bf16(ah, bw, acc2[f], 0, 0, 0);
        }
    }

    if (l15 < ncols) {
        const float b2 = bias2[l15];
#pragma unroll
        for (int f = 0; f < 2; ++f) {
#pragma unroll
            for (int r = 0; r < 4; ++r) {
                const int grow = rowblk + f * 16 + g * 4 + r;
                if (grow < nrows)
                    out[(size_t)grow * ncols + l15] = acc2[f][r] + b2;
            }
        }
    }
}

// ---------------- launch ----------------

extern "C" void kernel_launch(void* const* d_in, const int* in_sizes, int n_in,
                              void* d_out, int out_size, void* d_ws, size_t ws_size,
                              hipStream_t stream)
{
    const float* node_feat = (const float*)d_in[0];
    const int*   pair_idx  = (const int*)d_in[1];
    const float* W_agg     = (const float*)d_in[2];
    const float* b_agg     = (const float*)d_in[3];
    const float* We1       = (const float*)d_in[4];
    const float* be1       = (const float*)d_in[5];
    const float* We2       = (const float*)d_in[6];
    const float* be2       = (const float*)d_in[7];
    const float* Wn1       = (const float*)d_in[8];
    const float* bn1       = (const float*)d_in[9];
    const float* Wn2       = (const float*)d_in[10];
    const float* bn2       = (const float*)d_in[11];

    const int N = in_sizes[0] / D;   // 100000
    const int E = in_sizes[1] / 2;   // 262144

    float* out = (float*)d_out;
    char*  ws  = (char*)d_ws;

    short* WcT  = (short*)(ws + 0);        // 128 KB
    short* Wn1T = (short*)(ws + 131072);   // 128 KB
    short* We2T = (short*)(ws + 262144);   // 8 KB
    short* Wn2T = (short*)(ws + 270336);   // 8 KB
    float* bc   = (float*)(ws + 278528);   // 1 KB
    const size_t H_OFF = 524288;
    short* H = (short*)(ws + H_OFF);       // N*D*2 = 51.2 MB
    const size_t need = H_OFF + (size_t)N * D * 2;

    pre_bc<<<1, 256, 0, stream>>>(b_agg, We1, be1, bc);
    pre_wct<<<D, 256, 0, stream>>>(W_agg, We1, WcT);
    pre_wn1t<<<D, 256, 0, stream>>>(Wn1, Wn1T);
    pre_w2t<<<1, 256, 0, stream>>>(We2, Wn2, We2T, Wn2T);

    if (ws_size >= need) {
        node_h_gemm2<<<(N + 63) / 64, 512, 0, stream>>>(
            node_feat, WcT, Wn1T, bc, bn1, Wn2T, bn2, H, out, N);

        edge_gemv<<<(E + 255) / 256, 256, 0, stream>>>(
            H, pair_idx, We2T, be2, out + (size_t)2 * N, E);
    } else {
        fused_mlp<0><<<(N + 127) / 128, 256, 0, stream>>>(
            node_feat, nullptr, Wn1T, bn1, Wn2T, bn2, out, N, 2);

        fused_mlp<1><<<E / 128, 256, 0, stream>>>(
            node_feat, pair_idx, WcT, bc, We2T, be2, out + (size_t)2 * N, E, 5);
    }
}